// Round 3
// baseline (1020.565 us; speedup 1.0000x reference)
//
#include <hip/hip_runtime.h>
#include <hip/hip_bf16.h>
#include <stdint.h>

#define N_TOKENS 16384
#define D_IN 1024
#define D_OUT 1024
#define N_EXPS 8

typedef __bf16 bf16x8 __attribute__((ext_vector_type(8)));
typedef float f32x4 __attribute__((ext_vector_type(4)));

typedef __attribute__((address_space(1))) void gvoid_t;
typedef __attribute__((address_space(3))) void lvoid_t;

__device__ __forceinline__ void async_copy16(void* lds, const void* g) {
    __builtin_amdgcn_global_load_lds((gvoid_t*)g, (lvoid_t*)lds, 16, 0, 0);
}

__device__ __forceinline__ unsigned short f2bf_u16(float f) {
    union { __hip_bfloat16 h; unsigned short u; } cv;
    cv.h = __float2bfloat16(f);
    return cv.u;
}

// Kernel 1: gating softmax (fp32) + embs -> bf16 conversion. One wave per token.
__global__ __launch_bounds__(256) void gate_convert_kernel(
    const float* __restrict__ embs, const float* __restrict__ expsT,
    unsigned short* __restrict__ embs_bf, float* __restrict__ probs) {
    const int row  = blockIdx.x * 4 + (threadIdx.x >> 6);
    const int lane = threadIdx.x & 63;
    const float* er = embs + (size_t)row * D_IN;

    float s[N_EXPS];
#pragma unroll
    for (int e = 0; e < N_EXPS; ++e) s[e] = 0.f;

#pragma unroll
    for (int j = 0; j < 4; ++j) {
        const int chunk = j * 64 + lane;
        const float4 v = ((const float4*)er)[chunk];
        const int d = chunk * 4;
        const float vv[4] = {v.x, v.y, v.z, v.w};
#pragma unroll
        for (int q = 0; q < 4; ++q) {
            const float4 t0 = ((const float4*)(expsT + (size_t)(d + q) * N_EXPS))[0];
            const float4 t1 = ((const float4*)(expsT + (size_t)(d + q) * N_EXPS))[1];
            s[0] += vv[q] * t0.x; s[1] += vv[q] * t0.y;
            s[2] += vv[q] * t0.z; s[3] += vv[q] * t0.w;
            s[4] += vv[q] * t1.x; s[5] += vv[q] * t1.y;
            s[6] += vv[q] * t1.z; s[7] += vv[q] * t1.w;
        }
        ushort4 u;
        u.x = f2bf_u16(v.x); u.y = f2bf_u16(v.y);
        u.z = f2bf_u16(v.z); u.w = f2bf_u16(v.w);
        ((ushort4*)embs_bf)[(size_t)row * 256 + chunk] = u;
    }

#pragma unroll
    for (int off = 32; off; off >>= 1) {
#pragma unroll
        for (int e = 0; e < N_EXPS; ++e) s[e] += __shfl_xor(s[e], off, 64);
    }

    float mx = s[0];
#pragma unroll
    for (int e = 1; e < N_EXPS; ++e) mx = fmaxf(mx, s[e]);
    float pe[N_EXPS];
    float sum = 0.f;
#pragma unroll
    for (int e = 0; e < N_EXPS; ++e) { pe[e] = __expf(s[e] - mx); sum += pe[e]; }
    const float inv = 1.f / sum;
    if (lane == 0) {
#pragma unroll
        for (int e = 0; e < N_EXPS; ++e) probs[(size_t)row * N_EXPS + e] = pe[e] * inv;
    }
}

// Kernel 2: expert_W -> bf16 conversion + c[e][o] = dot(bias_e, W[e][o]). One wave per (e,o) row.
__global__ __launch_bounds__(256) void wconv_kernel(
    const float* __restrict__ W, const float* __restrict__ bias,
    unsigned short* __restrict__ Wbf, float* __restrict__ cvec) {
    const int gw   = blockIdx.x * 4 + (threadIdx.x >> 6);  // 0..8191 = e*1024+o
    const int lane = threadIdx.x & 63;
    const int e    = gw >> 10;
    const float* wr = W + (size_t)gw * D_IN;
    const float* br = bias + (size_t)e * D_IN;

    float dot = 0.f;
#pragma unroll
    for (int j = 0; j < 4; ++j) {
        const int chunk = j * 64 + lane;
        const float4 w4 = ((const float4*)wr)[chunk];
        const float4 b4 = ((const float4*)br)[chunk];
        dot += w4.x * b4.x + w4.y * b4.y + w4.z * b4.z + w4.w * b4.w;
        ushort4 u;
        u.x = f2bf_u16(w4.x); u.y = f2bf_u16(w4.y);
        u.z = f2bf_u16(w4.z); u.w = f2bf_u16(w4.w);
        ((ushort4*)Wbf)[(size_t)gw * 256 + chunk] = u;
    }
#pragma unroll
    for (int off = 32; off; off >>= 1) dot += __shfl_xor(dot, off, 64);
    if (lane == 0) cvec[gw] = dot;
}

// Kernel 3: fused 8-expert bf16 GEMM — 8-phase-class schedule (T2+T3+T4+T5).
// BM=256 BN=128 BK=64, 512 threads (8 waves, 4M x 2N), per-wave 64x64 output.
// Triple-buffered LDS (stage it+2 while computing it -> true counted vmcnt(6)),
// 2 sub-phases per K-tile {8 ds_read_b128 -> barrier -> setprio+16 MFMA -> barrier},
// st-swizzled LDS (linear gload_lds dest + inverse-swizzled global col + XOR'd read).
__global__ __launch_bounds__(512, 2) void moe_gemm_kernel(
    const __hip_bfloat16* __restrict__ Abf, const __hip_bfloat16* __restrict__ Wbf,
    const float* __restrict__ probs, const float* __restrict__ cvec,
    float* __restrict__ out_multi, float* __restrict__ out_exp) {
    constexpr int BM = 256, BN = 128, BK = 64;
    constexpr int NIT    = N_EXPS * (D_IN / BK);   // 128 iterations (expert-major)
    constexpr int ABYTES = BM * BK * 2;            // 32768
    constexpr int BBYTES = BN * BK * 2;            // 16384
    constexpr int BUFB   = ABYTES + BBYTES;        // 49152 per buffer
    extern __shared__ char smem[];                 // 3*BUFB + 8K(p) + 4K(c) = 159744 B
    float* p_lds = (float*)(smem + 3 * BUFB);          // [8][256]
    float* c_lds = (float*)(smem + 3 * BUFB + 8192);   // [8][128]

    const int tid  = threadIdx.x;
    const int lane = tid & 63;
    const int lm   = lane & 15;
    const int lq   = lane >> 4;
    const int wave = tid >> 6;       // 0..7
    const int wr   = wave >> 1;      // 0..3 (M)
    const int wc   = wave & 1;       // 0..1 (N)
    const int nT   = blockIdx.x & 7; // one N-panel per XCD -> B stays L2-resident
    const int mT   = blockIdx.x >> 3;
    const int m0   = mT * BM;
    const int n0   = nT * BN;

    // ---- staging geometry (rule #21: linear LDS dest, inverse-swizzled global src) ----
    // unit = 8KB = 64 rows x 64 cols bf16. thread t -> row t>>3, col8 (t&7)^((t>>3)&7).
    const int trow = tid >> 3;
    const int tcol = (tid & 7) ^ (trow & 7);
    const __hip_bfloat16* gA = Abf + (size_t)(m0 + trow) * D_IN + tcol * 8;
    const __hip_bfloat16* gB = Wbf + (size_t)(n0 + trow) * D_IN + tcol * 8;
    const int ldsoff = (tid & ~63) << 4;  // wave-uniform base within a unit (wave*1024)

    auto stage_h = [&](int it, int buf, int half) {
        const int e  = it >> 4;
        const int ko = (it & 15) * BK;
        char* base = smem + buf * BUFB;
        const __hip_bfloat16* gAk = gA + ko;
        const __hip_bfloat16* gBk = gB + (size_t)e * ((size_t)D_OUT * D_IN) + ko;
        if (half == 0) {
            async_copy16(base + 0 * 8192 + ldsoff, gAk + 0 * 64 * D_IN);
            async_copy16(base + 1 * 8192 + ldsoff, gAk + 1 * 64 * D_IN);
            async_copy16(base + ABYTES + 0 * 8192 + ldsoff, gBk);
        } else {
            async_copy16(base + 2 * 8192 + ldsoff, gAk + 2 * 64 * D_IN);
            async_copy16(base + 3 * 8192 + ldsoff, gAk + 3 * 64 * D_IN);
            async_copy16(base + ABYTES + 1 * 8192 + ldsoff, gBk + 64 * D_IN);
        }
    };

    // ---- p/c epilogue tables first (their vmcnt waits must not drain stage loads) ----
    for (int i = tid; i < N_EXPS * BM; i += 512)
        p_lds[(i >> 8) * 256 + (i & 255)] = probs[(size_t)(m0 + (i & 255)) * N_EXPS + (i >> 8)];
    for (int i = tid; i < N_EXPS * BN; i += 512)
        c_lds[(i >> 7) * 128 + (i & 127)] = cvec[(size_t)(i >> 7) * D_OUT + n0 + (i & 127)];

    // prologue: stage K-tiles 0 and 1
    stage_h(0, 0, 0); stage_h(0, 0, 1);
    stage_h(1, 1, 0); stage_h(1, 1, 1);

    // ---- fragment LDS offsets (precomputed, statically indexed; XOR-swizzled) ----
    const int axor = (lm & 7) << 4;
    int a_off0[4], a_off1[4], b_off0[4], b_off1[4];
#pragma unroll
    for (int t = 0; t < 4; ++t) {
        const int ra = (wr * 64 + t * 16 + lm) * 128 + lq * 16;
        const int rb = (wc * 64 + t * 16 + lm) * 128 + lq * 16;
        a_off0[t] = (ra +  0) ^ axor;
        a_off1[t] = (ra + 64) ^ axor;
        b_off0[t] = ABYTES + ((rb +  0) ^ axor);
        b_off1[t] = ABYTES + ((rb + 64) ^ axor);
    }

    f32x4 acc[4][4];
    f32x4 multi[4][4];
    const f32x4 fzero = {0.f, 0.f, 0.f, 0.f};
#pragma unroll
    for (int ti = 0; ti < 4; ++ti)
#pragma unroll
        for (int tj = 0; tj < 4; ++tj) { acc[ti][tj] = fzero; multi[ti][tj] = fzero; }

    // epilogue: val = dot - c_e[o]; nt-store expert_outputs; multi += p*val.
    auto epilogue = [&](int e) {
        float cv[4];
#pragma unroll
        for (int tj = 0; tj < 4; ++tj) cv[tj] = c_lds[e * 128 + wc * 64 + tj * 16 + lm];
#pragma unroll
        for (int ti = 0; ti < 4; ++ti) {
#pragma unroll
            for (int r = 0; r < 4; ++r) {
                const int rloc = wr * 64 + ti * 16 + lq * 4 + r;
                const int grow = m0 + rloc;
                const float p = p_lds[e * 256 + rloc];
                float* orow = out_exp + ((size_t)grow * N_EXPS + e) * D_OUT + n0 + wc * 64;
#pragma unroll
                for (int tj = 0; tj < 4; ++tj) {
                    const float val = acc[ti][tj][r] - cv[tj];
                    __builtin_nontemporal_store(val, &orow[tj * 16 + lm]);
                    multi[ti][tj][r] = fmaf(p, val, multi[ti][tj][r]);
                }
            }
        }
    };

    // acquire K-tile 0: own fills visible (lgkm), own stage(0) landed (vmcnt<=6), all waves synced.
    asm volatile("s_waitcnt lgkmcnt(0)" ::: "memory");
    asm volatile("s_waitcnt vmcnt(6)" ::: "memory");
    __builtin_amdgcn_s_barrier();
    __builtin_amdgcn_sched_barrier(0);

    int cur = 0;
    for (int it = 0; it < NIT; ++it) {
        const char* buf = smem + cur * BUFB;
        const int nb2 = (cur == 0) ? 2 : cur - 1;   // (cur+2)%3

        // ---------------- phase 0 (kk = 0) ----------------
        {
            bf16x8 a[4], b[4];
#pragma unroll
            for (int t = 0; t < 4; ++t) a[t] = *(const bf16x8*)(buf + a_off0[t]);
#pragma unroll
            for (int t = 0; t < 4; ++t) b[t] = *(const bf16x8*)(buf + b_off0[t]);
            if (it + 2 < NIT) stage_h(it + 2, nb2, 0);
            __builtin_amdgcn_sched_barrier(0);
            __builtin_amdgcn_s_barrier();
            __builtin_amdgcn_sched_barrier(0);
            __builtin_amdgcn_s_setprio(1);
#pragma unroll
            for (int ti = 0; ti < 4; ++ti)
#pragma unroll
                for (int tj = 0; tj < 4; ++tj)
                    acc[ti][tj] = __builtin_amdgcn_mfma_f32_16x16x32_bf16(
                        a[ti], b[tj], acc[ti][tj], 0, 0, 0);
            __builtin_amdgcn_s_setprio(0);
            __builtin_amdgcn_sched_barrier(0);
            __builtin_amdgcn_s_barrier();
        }

        // ---------------- phase 1 (kk = 1) ----------------
        {
            bf16x8 a[4], b[4];
#pragma unroll
            for (int t = 0; t < 4; ++t) a[t] = *(const bf16x8*)(buf + a_off1[t]);
#pragma unroll
            for (int t = 0; t < 4; ++t) b[t] = *(const bf16x8*)(buf + b_off1[t]);
            if (it + 2 < NIT) stage_h(it + 2, nb2, 1);
            __builtin_amdgcn_sched_barrier(0);
            __builtin_amdgcn_s_barrier();
            __builtin_amdgcn_sched_barrier(0);
            __builtin_amdgcn_s_setprio(1);
#pragma unroll
            for (int ti = 0; ti < 4; ++ti)
#pragma unroll
                for (int tj = 0; tj < 4; ++tj)
                    acc[ti][tj] = __builtin_amdgcn_mfma_f32_16x16x32_bf16(
                        a[ti], b[tj], acc[ti][tj], 0, 0, 0);
            __builtin_amdgcn_s_setprio(0);
            __builtin_amdgcn_sched_barrier(0);
        }

        // ---- K-tile boundary: acquire it+1 (counted vmcnt: it+2's 6 loads may fly) ----
        if (it + 2 < NIT) {
            asm volatile("s_waitcnt vmcnt(6)" ::: "memory");
        } else if (it + 1 < NIT) {
            asm volatile("s_waitcnt vmcnt(0)" ::: "memory");
        }
        __builtin_amdgcn_s_barrier();

        if ((it & 15) == 15) {
            epilogue(it >> 4);
#pragma unroll
            for (int ti = 0; ti < 4; ++ti)
#pragma unroll
                for (int tj = 0; tj < 4; ++tj) acc[ti][tj] = fzero;
        }
        cur = (cur == 2) ? 0 : cur + 1;
    }

#pragma unroll
    for (int ti = 0; ti < 4; ++ti) {
#pragma unroll
        for (int r = 0; r < 4; ++r) {
            const int grow = m0 + wr * 64 + ti * 16 + lq * 4 + r;
            float* mrow = out_multi + (size_t)grow * D_OUT + n0 + wc * 64;
#pragma unroll
            for (int tj = 0; tj < 4; ++tj)
                __builtin_nontemporal_store(multi[ti][tj][r], &mrow[tj * 16 + lm]);
        }
    }
}

extern "C" void kernel_launch(void* const* d_in, const int* in_sizes, int n_in,
                              void* d_out, int out_size, void* d_ws, size_t ws_size,
                              hipStream_t stream) {
    const float* embs  = (const float*)d_in[0];   // [16384,1024]
    const float* expsT = (const float*)d_in[1];   // [1024,8]
    const float* bias  = (const float*)d_in[2];   // [8,1024]
    const float* W     = (const float*)d_in[3];   // [8,1024,1024]

    float* out_multi = (float*)d_out;                            // [16384,1024]
    float* out_exp   = (float*)d_out + (size_t)N_TOKENS * D_OUT; // [16384,8,1024]

    // workspace layout (~51 MB)
    char* ws = (char*)d_ws;
    unsigned short* embs_bf = (unsigned short*)ws;                         // 33,554,432 B
    unsigned short* W_bf    = (unsigned short*)(ws + 33554432);            // 16,777,216 B
    float*          probs   = (float*)(ws + 33554432 + 16777216);          //    524,288 B
    float*          cvec    = (float*)(ws + 33554432 + 16777216 + 524288); //     32,768 B

    constexpr int SMEM_BYTES = 3 * (256 * 64 * 2 + 128 * 64 * 2) + 8192 + 4096; // 159744
    static bool configured = false;
    if (!configured) {
        hipFuncSetAttribute(reinterpret_cast<const void*>(moe_gemm_kernel),
                            hipFuncAttributeMaxDynamicSharedMemorySize, SMEM_BYTES);
        configured = true;
    }

    gate_convert_kernel<<<N_TOKENS / 4, 256, 0, stream>>>(embs, expsT, embs_bf, probs);
    wconv_kernel<<<(N_EXPS * D_OUT) / 4, 256, 0, stream>>>(W, bias, W_bf, cvec);
    moe_gemm_kernel<<<(N_TOKENS / 256) * (D_OUT / 128), 512, SMEM_BYTES, stream>>>(
        (const __hip_bfloat16*)embs_bf, (const __hip_bfloat16*)W_bf,
        probs, cvec, out_multi, out_exp);
}

// Round 4
// 971.654 us; speedup vs baseline: 1.0503x; 1.0503x over previous
//
#include <hip/hip_runtime.h>
#include <hip/hip_bf16.h>
#include <stdint.h>

#define N_TOKENS 16384
#define D_IN 1024
#define D_OUT 1024
#define N_EXPS 8

typedef __bf16 bf16x8 __attribute__((ext_vector_type(8)));
typedef float f32x4 __attribute__((ext_vector_type(4)));

typedef __attribute__((address_space(1))) void gvoid_t;
typedef __attribute__((address_space(3))) void lvoid_t;

__device__ __forceinline__ void async_copy16(void* lds, const void* g) {
    __builtin_amdgcn_global_load_lds((gvoid_t*)g, (lvoid_t*)lds, 16, 0, 0);
}

__device__ __forceinline__ unsigned short f2bf_u16(float f) {
    union { __hip_bfloat16 h; unsigned short u; } cv;
    cv.h = __float2bfloat16(f);
    return cv.u;
}

// Kernel 1: gating softmax (fp32) + embs -> bf16 conversion. One wave per token.
__global__ __launch_bounds__(256) void gate_convert_kernel(
    const float* __restrict__ embs, const float* __restrict__ expsT,
    unsigned short* __restrict__ embs_bf, float* __restrict__ probs) {
    const int row  = blockIdx.x * 4 + (threadIdx.x >> 6);
    const int lane = threadIdx.x & 63;
    const float* er = embs + (size_t)row * D_IN;

    float s[N_EXPS];
#pragma unroll
    for (int e = 0; e < N_EXPS; ++e) s[e] = 0.f;

#pragma unroll
    for (int j = 0; j < 4; ++j) {
        const int chunk = j * 64 + lane;
        const float4 v = ((const float4*)er)[chunk];
        const int d = chunk * 4;
        const float vv[4] = {v.x, v.y, v.z, v.w};
#pragma unroll
        for (int q = 0; q < 4; ++q) {
            const float4 t0 = ((const float4*)(expsT + (size_t)(d + q) * N_EXPS))[0];
            const float4 t1 = ((const float4*)(expsT + (size_t)(d + q) * N_EXPS))[1];
            s[0] += vv[q] * t0.x; s[1] += vv[q] * t0.y;
            s[2] += vv[q] * t0.z; s[3] += vv[q] * t0.w;
            s[4] += vv[q] * t1.x; s[5] += vv[q] * t1.y;
            s[6] += vv[q] * t1.z; s[7] += vv[q] * t1.w;
        }
        ushort4 u;
        u.x = f2bf_u16(v.x); u.y = f2bf_u16(v.y);
        u.z = f2bf_u16(v.z); u.w = f2bf_u16(v.w);
        ((ushort4*)embs_bf)[(size_t)row * 256 + chunk] = u;
    }

#pragma unroll
    for (int off = 32; off; off >>= 1) {
#pragma unroll
        for (int e = 0; e < N_EXPS; ++e) s[e] += __shfl_xor(s[e], off, 64);
    }

    float mx = s[0];
#pragma unroll
    for (int e = 1; e < N_EXPS; ++e) mx = fmaxf(mx, s[e]);
    float pe[N_EXPS];
    float sum = 0.f;
#pragma unroll
    for (int e = 0; e < N_EXPS; ++e) { pe[e] = __expf(s[e] - mx); sum += pe[e]; }
    const float inv = 1.f / sum;
    if (lane == 0) {
#pragma unroll
        for (int e = 0; e < N_EXPS; ++e) probs[(size_t)row * N_EXPS + e] = pe[e] * inv;
    }
}

// Kernel 2: expert_W -> bf16 conversion + c[e][o] = dot(bias_e, W[e][o]). One wave per (e,o) row.
__global__ __launch_bounds__(256) void wconv_kernel(
    const float* __restrict__ W, const float* __restrict__ bias,
    unsigned short* __restrict__ Wbf, float* __restrict__ cvec) {
    const int gw   = blockIdx.x * 4 + (threadIdx.x >> 6);  // 0..8191 = e*1024+o
    const int lane = threadIdx.x & 63;
    const int e    = gw >> 10;
    const float* wr = W + (size_t)gw * D_IN;
    const float* br = bias + (size_t)e * D_IN;

    float dot = 0.f;
#pragma unroll
    for (int j = 0; j < 4; ++j) {
        const int chunk = j * 64 + lane;
        const float4 w4 = ((const float4*)wr)[chunk];
        const float4 b4 = ((const float4*)br)[chunk];
        dot += w4.x * b4.x + w4.y * b4.y + w4.z * b4.z + w4.w * b4.w;
        ushort4 u;
        u.x = f2bf_u16(w4.x); u.y = f2bf_u16(w4.y);
        u.z = f2bf_u16(w4.z); u.w = f2bf_u16(w4.w);
        ((ushort4*)Wbf)[(size_t)gw * 256 + chunk] = u;
    }
#pragma unroll
    for (int off = 32; off; off >>= 1) dot += __shfl_xor(dot, off, 64);
    if (lane == 0) cvec[gw] = dot;
}

// Kernel 3: fused 8-expert bf16 GEMM, QUAD-EXPERT grouped (A staged once per 4
// experts -> 2 A-passes total; HBM traffic is the binding pipe per R3 counters).
// BM=128 BN=128 BK=32, 512 threads (8 waves as 2M x 4N), per-wave 64x32 per expert.
// Triple-buffered LDS (40KB/buf), counted vmcnt(5), XOR-swizzled reads (2-way
// residual = free), setprio around MFMA cluster, nt output stores.
__global__ __launch_bounds__(512, 2) void moe_gemm_kernel(
    const __hip_bfloat16* __restrict__ Abf, const __hip_bfloat16* __restrict__ Wbf,
    const float* __restrict__ probs, const float* __restrict__ cvec,
    float* __restrict__ out_multi, float* __restrict__ out_exp) {
    constexpr int BM = 128, BN = 128, BK = 32, EG = 4;
    constexpr int NIT    = (N_EXPS / EG) * (D_IN / BK);   // 2 passes x 32 K-tiles = 64
    constexpr int ABYTES = BM * BK * 2;                   // 8192
    constexpr int EBYTES = BN * BK * 2;                   // 8192 per expert B tile
    constexpr int BUFB   = ABYTES + EG * EBYTES;          // 40960 per buffer
    extern __shared__ char smem[];                        // 3*BUFB + 4K(p) + 4K(c) = 131072
    float* p_lds = (float*)(smem + 3 * BUFB);             // [8][128]
    float* c_lds = (float*)(smem + 3 * BUFB + 4096);      // [8][128]

    const int tid  = threadIdx.x;
    const int lane = tid & 63;
    const int lm   = lane & 15;
    const int lq   = lane >> 4;
    const int wave = tid >> 6;       // 0..7
    const int wr   = wave >> 2;      // 0..1 (M)
    const int wc   = wave & 3;       // 0..3 (N)
    const int nT   = blockIdx.x & 7; // one N-panel per XCD -> B stays L2-resident
    const int mT   = blockIdx.x >> 3;
    const int m0   = mT * BM;
    const int n0   = nT * BN;

    // ---- staging geometry (rule #21: linear LDS dest + inverse-swizzled global col) ----
    // tile = 128 rows x 32 bf16 (64B rows = 4 x 16B slots). thread t -> row t>>2,
    // slot t&3; global col8 = (t&3) ^ ((t>>3)&3)  [involution per row-pair].
    const int trow = tid >> 2;                       // 0..127
    const int tcol = (tid & 3) ^ ((tid >> 3) & 3);   // swizzled 16B-chunk index
    const __hip_bfloat16* gA = Abf + (size_t)(m0 + trow) * D_IN + tcol * 8;
    const __hip_bfloat16* gB = Wbf + (size_t)(n0 + trow) * D_IN + tcol * 8;
    const int ldsoff = (tid & ~63) * 16;             // wave-uniform byte base (wave*1024)

    auto stage = [&](int it, int buf) {
        const int pass = it >> 5;                    // 0..1
        const int ko   = (it & 31) * BK;
        char* base = smem + buf * BUFB;
        async_copy16(base + ldsoff, gA + ko);
        const __hip_bfloat16* gBk = gB + ko + (size_t)(pass * EG) * ((size_t)D_OUT * D_IN);
#pragma unroll
        for (int el = 0; el < EG; ++el)
            async_copy16(base + ABYTES + el * EBYTES + ldsoff,
                         gBk + (size_t)el * ((size_t)D_OUT * D_IN));
    };

    // ---- p/c epilogue tables first (drained before stage issues -> vmcnt stays countable) ----
    for (int i = tid; i < N_EXPS * BM; i += 512)
        p_lds[(i >> 7) * 128 + (i & 127)] = probs[(size_t)(m0 + (i & 127)) * N_EXPS + (i >> 7)];
    for (int i = tid; i < N_EXPS * BN; i += 512)
        c_lds[(i >> 7) * 128 + (i & 127)] = cvec[(size_t)(i >> 7) * D_OUT + n0 + (i & 127)];
    __builtin_amdgcn_sched_barrier(0);

    // prologue: stage K-tiles 0 and 1
    stage(0, 0);
    stage(1, 1);

    // ---- fragment LDS byte offsets. Swizzle term is row-bits[2:1] = lm bits[2:1]
    // (frag rows differ only in bits >=4), so ONE term serves all fragments. ----
    const int sw     = (lq ^ ((lm >> 1) & 3)) * 16;
    const int a_base = (wr * 64 + lm) * 64 + sw;           // + mi*1024 (imm-folded)
    const int b_base = ABYTES + (wc * 32 + lm) * 64 + sw;  // + el*8192 + nj*1024 (imm-folded)

    f32x4 acc[EG][4][2];
    f32x4 multi[4][2];
    const f32x4 fzero = {0.f, 0.f, 0.f, 0.f};
#pragma unroll
    for (int el = 0; el < EG; ++el)
#pragma unroll
        for (int mi = 0; mi < 4; ++mi)
#pragma unroll
            for (int nj = 0; nj < 2; ++nj) acc[el][mi][nj] = fzero;
#pragma unroll
    for (int mi = 0; mi < 4; ++mi)
#pragma unroll
        for (int nj = 0; nj < 2; ++nj) multi[mi][nj] = fzero;

    // epilogue for one pass (4 experts): val = dot - c_e[o]; nt-store; multi += p*val.
    auto epilogue = [&](int ebase) {
#pragma unroll
        for (int el = 0; el < EG; ++el) {
            const int e = ebase + el;
            float cv[2];
#pragma unroll
            for (int nj = 0; nj < 2; ++nj) cv[nj] = c_lds[e * 128 + wc * 32 + nj * 16 + lm];
#pragma unroll
            for (int mi = 0; mi < 4; ++mi) {
#pragma unroll
                for (int r = 0; r < 4; ++r) {
                    const int rloc = wr * 64 + mi * 16 + lq * 4 + r;
                    const int grow = m0 + rloc;
                    const float p = p_lds[e * 128 + rloc];
                    float* orow = out_exp + ((size_t)grow * N_EXPS + e) * D_OUT + n0 + wc * 32;
#pragma unroll
                    for (int nj = 0; nj < 2; ++nj) {
                        const float val = acc[el][mi][nj][r] - cv[nj];
                        __builtin_nontemporal_store(val, &orow[nj * 16 + lm]);
                        multi[mi][nj][r] = fmaf(p, val, multi[mi][nj][r]);
                    }
                }
            }
        }
    };

    // acquire tile 0: own lgkm (p/c ds_writes) drained, stage(0) landed (5 of stage(1) fly).
    asm volatile("s_waitcnt lgkmcnt(0)" ::: "memory");
    asm volatile("s_waitcnt vmcnt(5)" ::: "memory");
    __builtin_amdgcn_s_barrier();
    __builtin_amdgcn_sched_barrier(0);

    int cur = 0;
    for (int it = 0; it < NIT; ++it) {
        const char* buf = smem + cur * BUFB;
        const int nb2 = (cur >= 1) ? cur - 1 : 2;   // (cur+2)%3

        // reads of tile `it` (acquired at previous boundary) + prefetch issue of it+2
        bf16x8 a[4], b[EG][2];
#pragma unroll
        for (int mi = 0; mi < 4; ++mi)
            a[mi] = *(const bf16x8*)(buf + a_base + mi * 1024);
#pragma unroll
        for (int el = 0; el < EG; ++el)
#pragma unroll
            for (int nj = 0; nj < 2; ++nj)
                b[el][nj] = *(const bf16x8*)(buf + b_base + el * EBYTES + nj * 1024);
        if (it + 2 < NIT) stage(it + 2, nb2);

        __builtin_amdgcn_sched_barrier(0);
        __builtin_amdgcn_s_barrier();              // phase alignment: reads/issue vs MFMA
        __builtin_amdgcn_sched_barrier(0);
        __builtin_amdgcn_s_setprio(1);
#pragma unroll
        for (int el = 0; el < EG; ++el)
#pragma unroll
            for (int mi = 0; mi < 4; ++mi)
#pragma unroll
                for (int nj = 0; nj < 2; ++nj)
                    acc[el][mi][nj] = __builtin_amdgcn_mfma_f32_16x16x32_bf16(
                        a[mi], b[el][nj], acc[el][mi][nj], 0, 0, 0);
        __builtin_amdgcn_s_setprio(0);
        __builtin_amdgcn_sched_barrier(0);

        // boundary: acquire it+1 (counted: it+2's 5 loads stay in flight)
        if (it + 2 < NIT) {
            asm volatile("s_waitcnt vmcnt(5)" ::: "memory");
        } else if (it + 1 < NIT) {
            asm volatile("s_waitcnt vmcnt(0)" ::: "memory");
        }
        __builtin_amdgcn_s_barrier();

        if ((it & 31) == 31) {
            epilogue((it >> 5) * EG);
#pragma unroll
            for (int el = 0; el < EG; ++el)
#pragma unroll
                for (int mi = 0; mi < 4; ++mi)
#pragma unroll
                    for (int nj = 0; nj < 2; ++nj) acc[el][mi][nj] = fzero;
        }
        cur = (cur == 2) ? 0 : cur + 1;
    }

#pragma unroll
    for (int mi = 0; mi < 4; ++mi) {
#pragma unroll
        for (int r = 0; r < 4; ++r) {
            const int grow = m0 + wr * 64 + mi * 16 + lq * 4 + r;
            float* mrow = out_multi + (size_t)grow * D_OUT + n0 + wc * 32;
#pragma unroll
            for (int nj = 0; nj < 2; ++nj)
                __builtin_nontemporal_store(multi[mi][nj][r], &mrow[nj * 16 + lm]);
        }
    }
}

extern "C" void kernel_launch(void* const* d_in, const int* in_sizes, int n_in,
                              void* d_out, int out_size, void* d_ws, size_t ws_size,
                              hipStream_t stream) {
    const float* embs  = (const float*)d_in[0];   // [16384,1024]
    const float* expsT = (const float*)d_in[1];   // [1024,8]
    const float* bias  = (const float*)d_in[2];   // [8,1024]
    const float* W     = (const float*)d_in[3];   // [8,1024,1024]

    float* out_multi = (float*)d_out;                            // [16384,1024]
    float* out_exp   = (float*)d_out + (size_t)N_TOKENS * D_OUT; // [16384,8,1024]

    // workspace layout (~51 MB)
    char* ws = (char*)d_ws;
    unsigned short* embs_bf = (unsigned short*)ws;                         // 33,554,432 B
    unsigned short* W_bf    = (unsigned short*)(ws + 33554432);            // 16,777,216 B
    float*          probs   = (float*)(ws + 33554432 + 16777216);          //    524,288 B
    float*          cvec    = (float*)(ws + 33554432 + 16777216 + 524288); //     32,768 B

    constexpr int SMEM_BYTES = 3 * 40960 + 4096 + 4096;  // 131072
    static bool configured = false;
    if (!configured) {
        hipFuncSetAttribute(reinterpret_cast<const void*>(moe_gemm_kernel),
                            hipFuncAttributeMaxDynamicSharedMemorySize, SMEM_BYTES);
        configured = true;
    }

    gate_convert_kernel<<<N_TOKENS / 4, 256, 0, stream>>>(embs, expsT, embs_bf, probs);
    wconv_kernel<<<(N_EXPS * D_OUT) / 4, 256, 0, stream>>>(W, bias, W_bf, cvec);
    moe_gemm_kernel<<<(N_TOKENS / 128) * (D_OUT / 128), 512, SMEM_BYTES, stream>>>(
        (const __hip_bfloat16*)embs_bf, (const __hip_bfloat16*)W_bf,
        probs, cvec, out_multi, out_exp);
}